// Round 4
// baseline (780.573 us; speedup 1.0000x reference)
//
#include <hip/hip_runtime.h>

// ---- problem dims (fixed by setup_inputs) ----
#define N_NODES 131072
#define DIM     128
#define NG      2048
#define HD      512

typedef unsigned short bf16_t;                       // raw bf16 bits
typedef short  short8 __attribute__((ext_vector_type(8)));
typedef float  f32x4  __attribute__((ext_vector_type(4)));

// ---- static device scratch (referenced ONLY from device code) ----
__device__ bf16_t g_fb [(size_t)N_NODES * DIM];      // features, bf16 (33.5 MB)
__device__ bf16_t g_wm [(size_t)HD * DIM];           // W_m, bf16
__device__ bf16_t g_wih[(size_t)4 * HD * 2 * HD];    // W_ih, bf16 (4.2 MB)
__device__ bf16_t g_whh[(size_t)4 * HD * HD];        // W_hh, bf16 (2.1 MB)
__device__ float  g_mf[(size_t)N_NODES * HD];        // 268 MB, fp32 m matrix
__device__ float  g_gates[(size_t)NG * 4 * HD];      // 16.8 MB
__device__ bf16_t g_Acat[(size_t)NG * 3 * HD];       // [h | r | h] per graph
__device__ float  g_c[(size_t)NG * HD];
__device__ float  g_h[(size_t)NG * HD];
__device__ int    g_start[NG + 1];
__device__ int    g_isbf16;                          // input float dtype flag
__device__ int    g_idx64;                           // graph_index int64 flag

__device__ __forceinline__ float bf2f(bf16_t u) {
  unsigned v = ((unsigned)u) << 16;
  float f;
  __builtin_memcpy(&f, &v, 4);
  return f;
}
__device__ __forceinline__ bf16_t f2bf(float f) {
  unsigned u;
  __builtin_memcpy(&u, &f, 4);
  u += 0x7FFFu + ((u >> 16) & 1u);   // RNE
  return (bf16_t)(u >> 16);
}
// dtype-agnostic scalar read of a "float tensor" input
__device__ __forceinline__ float rdf(const void* p, int i) {
  return g_isbf16 ? bf2f(((const bf16_t*)p)[i]) : ((const float*)p)[i];
}

// ---- dtype detection (one block; writes device flags) ----
__global__ void k_detect(const void* feat, const void* gi) {
  __shared__ int cnt;
  if (threadIdx.x == 0) cnt = 0;
  __syncthreads();
  // sample first 256 16-bit halves of features; bf16 data decodes ~100% sane,
  // fp32 data's mantissa-low halves have uniform exponents (~16% sane)
  bf16_t u = ((const bf16_t*)feat)[threadIdx.x];
  float v = bf2f(u);
  float a = fabsf(v);
  int ok = (v == v) && a >= 1e-6f && a <= 1e6f;
  atomicAdd(&cnt, ok);
  __syncthreads();
  if (threadIdx.x == 0) {
    g_isbf16 = (cnt >= 230);
    // sorted indices: last int32 word is ~2047 for int32 data, but the
    // high word of an int64 (value < 2^31) for int64 data -> 0
    g_idx64 = (((const int*)gi)[N_NODES - 1] == 0);
  }
}

// ---- fused conversion of all 4 matrix inputs to bf16 staging ----
#define NFP ((size_t)N_NODES * DIM / 2)
#define NWP ((size_t)HD * DIM / 2)
#define NIP ((size_t)4 * HD * 2 * HD / 2)
#define NHP ((size_t)4 * HD * HD / 2)
__global__ __launch_bounds__(256) void k_cvt_all(const void* f, const void* wm,
                                                 const void* wih, const void* whh) {
  const int isb = g_isbf16;
  size_t i = (size_t)blockIdx.x * 256 + threadIdx.x;
  const void* src; bf16_t* dst; size_t off;
  if (i < NFP)                   { src = f;   dst = g_fb;  off = i; }
  else if (i < NFP + NWP)        { src = wm;  dst = g_wm;  off = i - NFP; }
  else if (i < NFP + NWP + NIP)  { src = wih; dst = g_wih; off = i - NFP - NWP; }
  else if (i < NFP + NWP + NIP + NHP) { src = whh; dst = g_whh; off = i - NFP - NWP - NIP; }
  else return;
  unsigned o;
  if (isb) {
    o = ((const unsigned*)src)[off];                 // already a packed bf16 pair
  } else {
    float2 v = ((const float2*)src)[off];
    o = (unsigned)f2bf(v.x) | ((unsigned)f2bf(v.y) << 16);
  }
  ((unsigned*)dst)[off] = o;
}
#define CVT_BLOCKS ((int)((NFP + NWP + NIP + NHP + 255) / 256))

// ---- zero-init LSTM state + Acat ----
__global__ void k_init() {
  int i = blockIdx.x * 256 + threadIdx.x;            // 6144*256 = 1,572,864
  ((unsigned*)g_Acat)[i] = 0u;                       // NG*3*HD bf16 = 1.5M dwords
  if (i < NG * HD) g_c[i] = 0.f;
}

// ---- per-graph start offsets from sorted graph_index ----
__global__ void k_offsets(const void* giv) {
  int n = blockIdx.x * 256 + threadIdx.x;
  if (n >= N_NODES) return;
  const int idx64 = g_idx64;
  int g = idx64 ? (int)((const long long*)giv)[n] : ((const int*)giv)[n];
  if (n == 0) {
    for (int x = 0; x <= g; ++x) g_start[x] = 0;
  } else {
    int gp = idx64 ? (int)((const long long*)giv)[n - 1] : ((const int*)giv)[n - 1];
    for (int x = gp + 1; x <= g; ++x) g_start[x] = n;
  }
  if (n == N_NODES - 1) {
    for (int x = g + 1; x <= NG; ++x) g_start[x] = N_NODES;
  }
}

// ---- GEMM 1: m = features @ W_m^T + b_m  (M=131072, N=512, K=128), fp32 out
__global__ __launch_bounds__(256) void k_gemm_m(const void* __restrict__ bias) {
  const int t = threadIdx.x, lid = t & 63, wid = t >> 6;
  const int m0 = blockIdx.x * 64 + (wid >> 1) * 32;
  const int n0 = blockIdx.y * 64 + (wid & 1) * 32;
  const int rr = lid & 15, quad = lid >> 4;
  f32x4 acc[2][2] = {};
  const bf16_t* Ap = g_fb + (size_t)(m0 + rr) * DIM + quad * 8;
  const bf16_t* Bp = g_wm + (size_t)(n0 + rr) * DIM + quad * 8;
#pragma unroll
  for (int k0 = 0; k0 < DIM; k0 += 32) {
    short8 a0 = *(const short8*)(Ap + k0);
    short8 a1 = *(const short8*)(Ap + 16 * DIM + k0);
    short8 b0 = *(const short8*)(Bp + k0);
    short8 b1 = *(const short8*)(Bp + 16 * DIM + k0);
    acc[0][0] = __builtin_amdgcn_mfma_f32_16x16x32_bf16(a0, b0, acc[0][0], 0, 0, 0);
    acc[0][1] = __builtin_amdgcn_mfma_f32_16x16x32_bf16(a0, b1, acc[0][1], 0, 0, 0);
    acc[1][0] = __builtin_amdgcn_mfma_f32_16x16x32_bf16(a1, b0, acc[1][0], 0, 0, 0);
    acc[1][1] = __builtin_amdgcn_mfma_f32_16x16x32_bf16(a1, b1, acc[1][1], 0, 0, 0);
  }
#pragma unroll
  for (int i = 0; i < 2; ++i)
#pragma unroll
    for (int j = 0; j < 2; ++j) {
      int col = n0 + j * 16 + rr;
      float bv = rdf(bias, col);
#pragma unroll
      for (int r = 0; r < 4; ++r) {
        int row = m0 + i * 16 + quad * 4 + r;
        g_mf[(size_t)row * HD + col] = acc[i][j][r] + bv;
      }
    }
}

// ---- GEMM 2: gates = Acat @ [W_ih|W_hh]^T  (M=2048, N=2048, K=1536), f32 out
__global__ __launch_bounds__(256) void k_gemm_gates() {
  const int t = threadIdx.x, lid = t & 63, wid = t >> 6;
  const int m0 = blockIdx.x * 64 + (wid >> 1) * 32;
  const int n0 = blockIdx.y * 64 + (wid & 1) * 32;
  const int rr = lid & 15, quad = lid >> 4;
  f32x4 acc[2][2] = {};
  const bf16_t* Ap0 = g_Acat + (size_t)(m0 + rr) * 1536;
  const bf16_t* Ap1 = Ap0 + 16 * 1536;
  const bf16_t* Bih = g_wih + (size_t)(n0 + rr) * 1024;
  const bf16_t* Bhh = g_whh + (size_t)(n0 + rr) * 512;
  for (int k0 = 0; k0 < 1536; k0 += 32) {
    int kk = k0 + quad * 8;
    short8 a0 = *(const short8*)(Ap0 + kk);
    short8 a1 = *(const short8*)(Ap1 + kk);
    short8 b0, b1;
    if (k0 < 1024) {                                 // wave-uniform branch
      b0 = *(const short8*)(Bih + kk);
      b1 = *(const short8*)(Bih + 16 * 1024 + kk);
    } else {
      b0 = *(const short8*)(Bhh + kk - 1024);
      b1 = *(const short8*)(Bhh + 16 * 512 + kk - 1024);
    }
    acc[0][0] = __builtin_amdgcn_mfma_f32_16x16x32_bf16(a0, b0, acc[0][0], 0, 0, 0);
    acc[0][1] = __builtin_amdgcn_mfma_f32_16x16x32_bf16(a0, b1, acc[0][1], 0, 0, 0);
    acc[1][0] = __builtin_amdgcn_mfma_f32_16x16x32_bf16(a1, b0, acc[1][0], 0, 0, 0);
    acc[1][1] = __builtin_amdgcn_mfma_f32_16x16x32_bf16(a1, b1, acc[1][1], 0, 0, 0);
  }
#pragma unroll
  for (int i = 0; i < 2; ++i)
#pragma unroll
    for (int j = 0; j < 2; ++j)
#pragma unroll
      for (int r = 0; r < 4; ++r) {
        int row = m0 + i * 16 + quad * 4 + r;
        int col = n0 + j * 16 + rr;
        g_gates[(size_t)row * 2048 + col] = acc[i][j][r];
      }
}

// ---- LSTM cell elementwise ----
__global__ __launch_bounds__(256) void k_lstm(const void* __restrict__ b_ih,
                                              const void* __restrict__ b_hh,
                                              void* __restrict__ out) {
  int idx = blockIdx.x * 256 + threadIdx.x;          // NG*HD threads
  int g = idx >> 9, j = idx & 511;
  const float* grow = g_gates + (size_t)g * 2048;
  float xi = grow[j]        + rdf(b_ih, j)        + rdf(b_hh, j);
  float xf = grow[j + 512]  + rdf(b_ih, j + 512)  + rdf(b_hh, j + 512);
  float xg = grow[j + 1024] + rdf(b_ih, j + 1024) + rdf(b_hh, j + 1024);
  float xo = grow[j + 1536] + rdf(b_ih, j + 1536) + rdf(b_hh, j + 1536);
  float si = 1.f / (1.f + __expf(-xi));
  float sf = 1.f / (1.f + __expf(-xf));
  float tg = tanhf(xg);
  float so = 1.f / (1.f + __expf(-xo));
  float cn = sf * g_c[idx] + si * tg;
  float hn = so * tanhf(cn);
  g_c[idx] = cn;
  g_h[idx] = hn;
  bf16_t hb = f2bf(hn);
  g_Acat[(size_t)g * 1536 + j] = hb;                 // q_star[0:H] = h
  g_Acat[(size_t)g * 1536 + 1024 + j] = hb;          // concat h for W_hh
  if (g_isbf16) ((bf16_t*)out)[(size_t)g * 1024 + j] = hb;
  else          ((float*)out)[(size_t)g * 1024 + j] = hn;
}

// ---- attention: single-pass online softmax + weighted sum, 1 block/graph ----
__global__ __launch_bounds__(256) void k_attn(void* __restrict__ out) {
  const int g = blockIdx.x;
  const int t = threadIdx.x, lid = t & 63, wid = t >> 6;
  __shared__ float s_m[4], s_l[4];
  __shared__ float s_r[4][HD];
  const int s = g_start[g], e = g_start[g + 1];
  // per-lane h chunk (8 consecutive dims) held in registers for all nodes
  float hreg[8];
  *(float4*)(hreg)     = *(const float4*)(g_h + (size_t)g * HD + lid * 8);
  *(float4*)(hreg + 4) = *(const float4*)(g_h + (size_t)g * HD + lid * 8 + 4);
  float mrun = -3.0e38f, lsum = 0.f;
  float racc[8] = {0.f, 0.f, 0.f, 0.f, 0.f, 0.f, 0.f, 0.f};
  for (int n = s + wid; n < e; n += 4) {
    const float* Mp = g_mf + (size_t)n * HD + lid * 8;
    float mv[8];
    *(float4*)(mv)     = *(const float4*)(Mp);
    *(float4*)(mv + 4) = *(const float4*)(Mp + 4);
    float d = 0.f;
#pragma unroll
    for (int j = 0; j < 8; ++j) d += mv[j] * hreg[j];
#pragma unroll
    for (int o = 32; o > 0; o >>= 1) d += __shfl_xor(d, o, 64);
    if (d > mrun) {                                  // wave-uniform branch
      float sc = __expf(mrun - d);
      lsum *= sc;
#pragma unroll
      for (int j = 0; j < 8; ++j) racc[j] *= sc;
      mrun = d;
    }
    float w = __expf(d - mrun);
    lsum += w;
#pragma unroll
    for (int j = 0; j < 8; ++j) racc[j] += w * mv[j];
  }
  if (lid == 0) s_m[wid] = mrun;
  __syncthreads();
  float gmax = fmaxf(fmaxf(s_m[0], s_m[1]), fmaxf(s_m[2], s_m[3]));
  float sc = (mrun > -1.0e38f) ? __expf(mrun - gmax) : 0.f;
#pragma unroll
  for (int j = 0; j < 8; ++j) s_r[wid][lid * 8 + j] = racc[j] * sc;
  if (lid == 0) s_l[wid] = lsum * sc;
  __syncthreads();
  float tot = s_l[0] + s_l[1] + s_l[2] + s_l[3];
  float inv = 1.f / (tot + 1e-7f);
  const int isb = g_isbf16;
  for (int d0 = t; d0 < HD; d0 += 256) {
    float rv = (s_r[0][d0] + s_r[1][d0] + s_r[2][d0] + s_r[3][d0]) * inv;
    g_Acat[(size_t)g * 1536 + 512 + d0] = f2bf(rv);  // q_star[H:2H] = r
    if (isb) ((bf16_t*)out)[(size_t)g * 1024 + 512 + d0] = f2bf(rv);
    else     ((float*)out)[(size_t)g * 1024 + 512 + d0] = rv;
  }
}

extern "C" void kernel_launch(void* const* d_in, const int* in_sizes, int n_in,
                              void* d_out, int out_size, void* d_ws, size_t ws_size,
                              hipStream_t stream) {
  const void* features = d_in[0];
  const void* gidx     = d_in[1];
  const void* W_m      = d_in[2];
  const void* b_m      = d_in[3];
  const void* W_ih     = d_in[4];
  const void* W_hh     = d_in[5];
  const void* b_ih     = d_in[6];
  const void* b_hh     = d_in[7];

  k_detect<<<1, 256, 0, stream>>>(features, gidx);
  k_cvt_all<<<CVT_BLOCKS, 256, 0, stream>>>(features, W_m, W_ih, W_hh);
  k_init<<<6144, 256, 0, stream>>>();
  k_offsets<<<N_NODES / 256, 256, 0, stream>>>(gidx);
  k_gemm_m<<<dim3(N_NODES / 64, HD / 64), 256, 0, stream>>>(b_m);
  for (int loop = 0; loop < 3; ++loop) {
    k_gemm_gates<<<dim3(32, 32), 256, 0, stream>>>();
    k_lstm<<<NG * HD / 256, 256, 0, stream>>>(b_ih, b_hh, d_out);
    k_attn<<<NG, 256, 0, stream>>>(d_out);
  }
}

// Round 5
// 730.577 us; speedup vs baseline: 1.0684x; 1.0684x over previous
//
#include <hip/hip_runtime.h>

// ---- problem dims (fixed by setup_inputs) ----
#define N_NODES 131072
#define DIM     128
#define NG      2048
#define HD      512

typedef unsigned short bf16_t;                       // raw bf16 bits
typedef short  short8 __attribute__((ext_vector_type(8)));
typedef float  f32x4  __attribute__((ext_vector_type(4)));

// ---- static device scratch (referenced ONLY from device code) ----
__device__ bf16_t g_fb [(size_t)N_NODES * DIM];      // features, bf16 (33.5 MB)
__device__ bf16_t g_wm [(size_t)HD * DIM];           // W_m, bf16
__device__ bf16_t g_wih[(size_t)4 * HD * 2 * HD];    // W_ih, bf16 (4.2 MB)
__device__ bf16_t g_whh[(size_t)4 * HD * HD];        // W_hh, bf16 (2.1 MB)
__device__ float  g_mf[(size_t)N_NODES * HD];        // 268 MB, fp32 m matrix
__device__ float  g_gates[(size_t)NG * 4 * HD];      // 16.8 MB
__device__ bf16_t g_Acat[(size_t)NG * 3 * HD];       // [h | r | h] per graph
__device__ float  g_c[(size_t)NG * HD];
__device__ float  g_h[(size_t)NG * HD];
__device__ int    g_start[NG + 1];
__device__ int    g_isbf16;                          // input float dtype flag
__device__ int    g_idx64;                           // graph_index int64 flag

__device__ __forceinline__ float bf2f(bf16_t u) {
  unsigned v = ((unsigned)u) << 16;
  float f;
  __builtin_memcpy(&f, &v, 4);
  return f;
}
__device__ __forceinline__ bf16_t f2bf(float f) {
  unsigned u;
  __builtin_memcpy(&u, &f, 4);
  u += 0x7FFFu + ((u >> 16) & 1u);   // RNE
  return (bf16_t)(u >> 16);
}
__device__ __forceinline__ float rdf(const void* p, int i) {
  return g_isbf16 ? bf2f(((const bf16_t*)p)[i]) : ((const float*)p)[i];
}

// ---- dtype detection (one block; writes device flags) ----
__global__ void k_detect(const void* feat, const void* gi) {
  __shared__ int cnt;
  if (threadIdx.x == 0) cnt = 0;
  __syncthreads();
  bf16_t u = ((const bf16_t*)feat)[threadIdx.x];
  float v = bf2f(u);
  float a = fabsf(v);
  int ok = (v == v) && a >= 1e-6f && a <= 1e6f;
  atomicAdd(&cnt, ok);
  __syncthreads();
  if (threadIdx.x == 0) {
    g_isbf16 = (cnt >= 230);
    g_idx64 = (((const int*)gi)[N_NODES - 1] == 0);
  }
}

// ---- fused conversion of all 4 matrix inputs to bf16 staging ----
#define NFP ((size_t)N_NODES * DIM / 2)
#define NWP ((size_t)HD * DIM / 2)
#define NIP ((size_t)4 * HD * 2 * HD / 2)
#define NHP ((size_t)4 * HD * HD / 2)
__global__ __launch_bounds__(256) void k_cvt_all(const void* f, const void* wm,
                                                 const void* wih, const void* whh) {
  const int isb = g_isbf16;
  size_t i = (size_t)blockIdx.x * 256 + threadIdx.x;
  const void* src; bf16_t* dst; size_t off;
  if (i < NFP)                   { src = f;   dst = g_fb;  off = i; }
  else if (i < NFP + NWP)        { src = wm;  dst = g_wm;  off = i - NFP; }
  else if (i < NFP + NWP + NIP)  { src = wih; dst = g_wih; off = i - NFP - NWP; }
  else if (i < NFP + NWP + NIP + NHP) { src = whh; dst = g_whh; off = i - NFP - NWP - NIP; }
  else return;
  unsigned o;
  if (isb) {
    o = ((const unsigned*)src)[off];
  } else {
    float2 v = ((const float2*)src)[off];
    o = (unsigned)f2bf(v.x) | ((unsigned)f2bf(v.y) << 16);
  }
  ((unsigned*)dst)[off] = o;
}
#define CVT_BLOCKS ((int)((NFP + NWP + NIP + NHP + 255) / 256))

// ---- zero-init LSTM state + Acat ----
__global__ void k_init() {
  int i = blockIdx.x * 256 + threadIdx.x;            // 6144*256 = 1,572,864
  ((unsigned*)g_Acat)[i] = 0u;
  if (i < NG * HD) g_c[i] = 0.f;
}

// ---- per-graph start offsets from sorted graph_index ----
__global__ void k_offsets(const void* giv) {
  int n = blockIdx.x * 256 + threadIdx.x;
  if (n >= N_NODES) return;
  const int idx64 = g_idx64;
  int g = idx64 ? (int)((const long long*)giv)[n] : ((const int*)giv)[n];
  if (n == 0) {
    for (int x = 0; x <= g; ++x) g_start[x] = 0;
  } else {
    int gp = idx64 ? (int)((const long long*)giv)[n - 1] : ((const int*)giv)[n - 1];
    for (int x = gp + 1; x <= g; ++x) g_start[x] = n;
  }
  if (n == N_NODES - 1) {
    for (int x = g + 1; x <= NG; ++x) g_start[x] = N_NODES;
  }
}

// ---- GEMM 1: m = features @ W_m^T + b_m  (M=131072, N=512, K=128), fp32 out
// One block per 64-row strip; A-frags register-resident across all 8 col tiles.
__global__ __launch_bounds__(256) void k_gemm_m(const void* __restrict__ bias) {
  const int t = threadIdx.x, lid = t & 63, wid = t >> 6;
  const int m0 = blockIdx.x * 64 + (wid >> 1) * 32;
  const int rr = lid & 15, quad = lid >> 4;
  // load this wave's A fragments once (32 rows x 128 k), 32 VGPRs
  short8 Af[4][2];
  const bf16_t* Ap = g_fb + (size_t)(m0 + rr) * DIM + quad * 8;
#pragma unroll
  for (int k = 0; k < 4; ++k) {
    Af[k][0] = *(const short8*)(Ap + k * 32);
    Af[k][1] = *(const short8*)(Ap + 16 * DIM + k * 32);
  }
  for (int nt = 0; nt < 8; ++nt) {
    const int n0 = nt * 64 + (wid & 1) * 32;
    const bf16_t* Bp = g_wm + (size_t)(n0 + rr) * DIM + quad * 8;
    f32x4 acc[2][2] = {};
#pragma unroll
    for (int k = 0; k < 4; ++k) {
      short8 b0 = *(const short8*)(Bp + k * 32);
      short8 b1 = *(const short8*)(Bp + 16 * DIM + k * 32);
      acc[0][0] = __builtin_amdgcn_mfma_f32_16x16x32_bf16(Af[k][0], b0, acc[0][0], 0, 0, 0);
      acc[0][1] = __builtin_amdgcn_mfma_f32_16x16x32_bf16(Af[k][0], b1, acc[0][1], 0, 0, 0);
      acc[1][0] = __builtin_amdgcn_mfma_f32_16x16x32_bf16(Af[k][1], b0, acc[1][0], 0, 0, 0);
      acc[1][1] = __builtin_amdgcn_mfma_f32_16x16x32_bf16(Af[k][1], b1, acc[1][1], 0, 0, 0);
    }
#pragma unroll
    for (int i = 0; i < 2; ++i)
#pragma unroll
      for (int j = 0; j < 2; ++j) {
        int col = n0 + j * 16 + rr;
        float bv = rdf(bias, col);
#pragma unroll
        for (int r = 0; r < 4; ++r) {
          int row = m0 + i * 16 + quad * 4 + r;
          g_mf[(size_t)row * HD + col] = acc[i][j][r] + bv;
        }
      }
  }
}

// ---- GEMM 2: gates = Acat @ [W_ih|W_hh]^T  (M=2048, N=2048, K=1536), f32 out
__global__ __launch_bounds__(256) void k_gemm_gates() {
  const int t = threadIdx.x, lid = t & 63, wid = t >> 6;
  const int m0 = blockIdx.x * 64 + (wid >> 1) * 32;
  const int n0 = blockIdx.y * 64 + (wid & 1) * 32;
  const int rr = lid & 15, quad = lid >> 4;
  f32x4 acc[2][2] = {};
  const bf16_t* Ap0 = g_Acat + (size_t)(m0 + rr) * 1536 + quad * 8;
  const bf16_t* Ap1 = Ap0 + 16 * 1536;
  const bf16_t* Bih = g_wih + (size_t)(n0 + rr) * 1024 + quad * 8;
  const bf16_t* Bhh = g_whh + (size_t)(n0 + rr) * 512 + quad * 8;
#pragma unroll 4
  for (int k0 = 0; k0 < 1024; k0 += 32) {
    short8 a0 = *(const short8*)(Ap0 + k0);
    short8 a1 = *(const short8*)(Ap1 + k0);
    short8 b0 = *(const short8*)(Bih + k0);
    short8 b1 = *(const short8*)(Bih + 16 * 1024 + k0);
    acc[0][0] = __builtin_amdgcn_mfma_f32_16x16x32_bf16(a0, b0, acc[0][0], 0, 0, 0);
    acc[0][1] = __builtin_amdgcn_mfma_f32_16x16x32_bf16(a0, b1, acc[0][1], 0, 0, 0);
    acc[1][0] = __builtin_amdgcn_mfma_f32_16x16x32_bf16(a1, b0, acc[1][0], 0, 0, 0);
    acc[1][1] = __builtin_amdgcn_mfma_f32_16x16x32_bf16(a1, b1, acc[1][1], 0, 0, 0);
  }
#pragma unroll 4
  for (int k0 = 0; k0 < 512; k0 += 32) {
    short8 a0 = *(const short8*)(Ap0 + 1024 + k0);
    short8 a1 = *(const short8*)(Ap1 + 1024 + k0);
    short8 b0 = *(const short8*)(Bhh + k0);
    short8 b1 = *(const short8*)(Bhh + 16 * 512 + k0);
    acc[0][0] = __builtin_amdgcn_mfma_f32_16x16x32_bf16(a0, b0, acc[0][0], 0, 0, 0);
    acc[0][1] = __builtin_amdgcn_mfma_f32_16x16x32_bf16(a0, b1, acc[0][1], 0, 0, 0);
    acc[1][0] = __builtin_amdgcn_mfma_f32_16x16x32_bf16(a1, b0, acc[1][0], 0, 0, 0);
    acc[1][1] = __builtin_amdgcn_mfma_f32_16x16x32_bf16(a1, b1, acc[1][1], 0, 0, 0);
  }
#pragma unroll
  for (int i = 0; i < 2; ++i)
#pragma unroll
    for (int j = 0; j < 2; ++j)
#pragma unroll
      for (int r = 0; r < 4; ++r) {
        int row = m0 + i * 16 + quad * 4 + r;
        int col = n0 + j * 16 + rr;
        g_gates[(size_t)row * 2048 + col] = acc[i][j][r];
      }
}

// ---- LSTM cell elementwise ----
__global__ __launch_bounds__(256) void k_lstm(const void* __restrict__ b_ih,
                                              const void* __restrict__ b_hh,
                                              void* __restrict__ out) {
  int idx = blockIdx.x * 256 + threadIdx.x;          // NG*HD threads
  int g = idx >> 9, j = idx & 511;
  const float* grow = g_gates + (size_t)g * 2048;
  float xi = grow[j]        + rdf(b_ih, j)        + rdf(b_hh, j);
  float xf = grow[j + 512]  + rdf(b_ih, j + 512)  + rdf(b_hh, j + 512);
  float xg = grow[j + 1024] + rdf(b_ih, j + 1024) + rdf(b_hh, j + 1024);
  float xo = grow[j + 1536] + rdf(b_ih, j + 1536) + rdf(b_hh, j + 1536);
  float si = 1.f / (1.f + __expf(-xi));
  float sf = 1.f / (1.f + __expf(-xf));
  float tg = tanhf(xg);
  float so = 1.f / (1.f + __expf(-xo));
  float cn = sf * g_c[idx] + si * tg;
  float hn = so * tanhf(cn);
  g_c[idx] = cn;
  g_h[idx] = hn;
  bf16_t hb = f2bf(hn);
  g_Acat[(size_t)g * 1536 + j] = hb;
  g_Acat[(size_t)g * 1536 + 1024 + j] = hb;
  if (g_isbf16) ((bf16_t*)out)[(size_t)g * 1024 + j] = hb;
  else          ((float*)out)[(size_t)g * 1024 + j] = hn;
}

// ---- attention: single-pass online softmax, 2-node unroll, 1 block/graph ----
__global__ __launch_bounds__(256) void k_attn(void* __restrict__ out) {
  const int g = blockIdx.x;
  const int t = threadIdx.x, lid = t & 63, wid = t >> 6;
  __shared__ float s_m[4], s_l[4];
  __shared__ float s_r[4][HD];
  const int s = g_start[g], e = g_start[g + 1];
  float hreg[8];
  *(float4*)(hreg)     = *(const float4*)(g_h + (size_t)g * HD + lid * 8);
  *(float4*)(hreg + 4) = *(const float4*)(g_h + (size_t)g * HD + lid * 8 + 4);
  float mrun = -3.0e38f, lsum = 0.f;
  float racc[8] = {0.f, 0.f, 0.f, 0.f, 0.f, 0.f, 0.f, 0.f};
  int n = s + wid;
  for (; n + 4 < e; n += 8) {                        // two nodes per iteration
    const float* Mp1 = g_mf + (size_t)n * HD + lid * 8;
    const float* Mp2 = g_mf + (size_t)(n + 4) * HD + lid * 8;
    float mv1[8], mv2[8];
    *(float4*)(mv1)     = *(const float4*)(Mp1);
    *(float4*)(mv1 + 4) = *(const float4*)(Mp1 + 4);
    *(float4*)(mv2)     = *(const float4*)(Mp2);
    *(float4*)(mv2 + 4) = *(const float4*)(Mp2 + 4);
    float d1 = 0.f, d2 = 0.f;
#pragma unroll
    for (int j = 0; j < 8; ++j) { d1 += mv1[j] * hreg[j]; d2 += mv2[j] * hreg[j]; }
#pragma unroll
    for (int o = 32; o > 0; o >>= 1) {
      d1 += __shfl_xor(d1, o, 64);
      d2 += __shfl_xor(d2, o, 64);
    }
    float mnew = fmaxf(mrun, fmaxf(d1, d2));
    float sc = __expf(mrun - mnew);
    float w1 = __expf(d1 - mnew), w2 = __expf(d2 - mnew);
    lsum = lsum * sc + w1 + w2;
#pragma unroll
    for (int j = 0; j < 8; ++j) racc[j] = racc[j] * sc + w1 * mv1[j] + w2 * mv2[j];
    mrun = mnew;
  }
  if (n < e) {                                       // tail node
    const float* Mp = g_mf + (size_t)n * HD + lid * 8;
    float mv[8];
    *(float4*)(mv)     = *(const float4*)(Mp);
    *(float4*)(mv + 4) = *(const float4*)(Mp + 4);
    float d = 0.f;
#pragma unroll
    for (int j = 0; j < 8; ++j) d += mv[j] * hreg[j];
#pragma unroll
    for (int o = 32; o > 0; o >>= 1) d += __shfl_xor(d, o, 64);
    float mnew = fmaxf(mrun, d);
    float sc = __expf(mrun - mnew);
    float w = __expf(d - mnew);
    lsum = lsum * sc + w;
#pragma unroll
    for (int j = 0; j < 8; ++j) racc[j] = racc[j] * sc + w * mv[j];
    mrun = mnew;
  }
  if (lid == 0) s_m[wid] = mrun;
  __syncthreads();
  float gmax = fmaxf(fmaxf(s_m[0], s_m[1]), fmaxf(s_m[2], s_m[3]));
  float sc = (mrun > -1.0e38f) ? __expf(mrun - gmax) : 0.f;
#pragma unroll
  for (int j = 0; j < 8; ++j) s_r[wid][lid * 8 + j] = racc[j] * sc;
  if (lid == 0) s_l[wid] = lsum * sc;
  __syncthreads();
  float tot = s_l[0] + s_l[1] + s_l[2] + s_l[3];
  float inv = 1.f / (tot + 1e-7f);
  const int isb = g_isbf16;
  for (int d0 = t; d0 < HD; d0 += 256) {
    float rv = (s_r[0][d0] + s_r[1][d0] + s_r[2][d0] + s_r[3][d0]) * inv;
    g_Acat[(size_t)g * 1536 + 512 + d0] = f2bf(rv);
    if (isb) ((bf16_t*)out)[(size_t)g * 1024 + 512 + d0] = f2bf(rv);
    else     ((float*)out)[(size_t)g * 1024 + 512 + d0] = rv;
  }
}

extern "C" void kernel_launch(void* const* d_in, const int* in_sizes, int n_in,
                              void* d_out, int out_size, void* d_ws, size_t ws_size,
                              hipStream_t stream) {
  const void* features = d_in[0];
  const void* gidx     = d_in[1];
  const void* W_m      = d_in[2];
  const void* b_m      = d_in[3];
  const void* W_ih     = d_in[4];
  const void* W_hh     = d_in[5];
  const void* b_ih     = d_in[6];
  const void* b_hh     = d_in[7];

  k_detect<<<1, 256, 0, stream>>>(features, gidx);
  k_cvt_all<<<CVT_BLOCKS, 256, 0, stream>>>(features, W_m, W_ih, W_hh);
  k_init<<<6144, 256, 0, stream>>>();
  k_offsets<<<N_NODES / 256, 256, 0, stream>>>(gidx);
  k_gemm_m<<<N_NODES / 64, 256, 0, stream>>>(b_m);
  for (int loop = 0; loop < 3; ++loop) {
    k_gemm_gates<<<dim3(32, 32), 256, 0, stream>>>();
    k_lstm<<<NG * HD / 256, 256, 0, stream>>>(b_ih, b_hh, d_out);
    k_attn<<<NG, 256, 0, stream>>>(d_out);
  }
}

// Round 6
// 403.862 us; speedup vs baseline: 1.9328x; 1.8090x over previous
//
#include <hip/hip_runtime.h>

// ---- problem dims (fixed by setup_inputs) ----
#define N_NODES 131072
#define DIM     128
#define NG      2048
#define HD      512

typedef unsigned short u16;
typedef _Float16 half8 __attribute__((ext_vector_type(8)));
typedef short  short8 __attribute__((ext_vector_type(8)));
typedef float  f32x4  __attribute__((ext_vector_type(4)));

// ---- static device scratch (referenced ONLY from device code) ----
__device__ u16   g_fb[(size_t)N_NODES * DIM];     // features fp16 (33.5 MB)
__device__ u16   g_wm[(size_t)HD * DIM];          // W_m fp16
__device__ u16   g_wg[(size_t)2048 * 1024];       // [Wih[:,:H]+Whh | Wih[:,H:]] fp16
__device__ u16   g_m16[(size_t)N_NODES * HD];     // m fp16 (134 MB, L3-resident)
__device__ float g_gates[(size_t)NG * 2048];      // 16.8 MB
__device__ u16   g_Acat[(size_t)NG * 1024];       // [h | r] fp16, 4 MB
__device__ float g_c[(size_t)NG * HD];
__device__ float g_h[(size_t)NG * HD];
__device__ int   g_start[NG + 1];
__device__ int   g_isbf16;
__device__ int   g_idx64;

__device__ __forceinline__ float bf2f(u16 u) {
  unsigned v = ((unsigned)u) << 16;
  float f; __builtin_memcpy(&f, &v, 4); return f;
}
__device__ __forceinline__ u16 f2bf(float f) {
  unsigned u; __builtin_memcpy(&u, &f, 4);
  u += 0x7FFFu + ((u >> 16) & 1u);
  return (u16)(u >> 16);
}
__device__ __forceinline__ u16 f2h(float f) {
  _Float16 h = (_Float16)f; u16 u; __builtin_memcpy(&u, &h, 2); return u;
}
__device__ __forceinline__ float rdf(const void* p, int i) {
  return g_isbf16 ? bf2f(((const u16*)p)[i]) : ((const float*)p)[i];
}

#define GLD16(gp, lp) __builtin_amdgcn_global_load_lds(                          \
    (const __attribute__((address_space(1))) void*)(gp),                         \
    (__attribute__((address_space(3))) void*)(lp), 16, 0, 0)

// ---- dtype detection ----
__global__ void k_detect(const void* feat, const void* gi) {
  __shared__ int cnt;
  if (threadIdx.x == 0) cnt = 0;
  __syncthreads();
  u16 u = ((const u16*)feat)[threadIdx.x];
  float v = bf2f(u);
  float a = fabsf(v);
  int ok = (v == v) && a >= 1e-6f && a <= 1e6f;
  atomicAdd(&cnt, ok);
  __syncthreads();
  if (threadIdx.x == 0) {
    g_isbf16 = (cnt >= 230);
    g_idx64 = (((const int*)gi)[N_NODES - 1] == 0);
  }
}

// ---- conversion: features/W_m -> fp16; build Wg = [Wih_l + Whh | Wih_r] fp16
#define NFP ((size_t)N_NODES * DIM / 2)
#define NWP ((size_t)HD * DIM / 2)
#define NWG ((size_t)2048 * 1024 / 2)
__global__ __launch_bounds__(256) void k_cvt_all(const void* f, const void* wm,
                                                 const void* wih, const void* whh) {
  const int isb = g_isbf16;
  size_t i = (size_t)blockIdx.x * 256 + threadIdx.x;
  if (i < NFP + NWP) {
    const void* src = (i < NFP) ? f : wm;
    u16* dst = (i < NFP) ? g_fb : g_wm;
    size_t off = (i < NFP) ? i : i - NFP;
    float v0, v1;
    if (isb) {
      unsigned pr = ((const unsigned*)src)[off];
      v0 = bf2f((u16)pr); v1 = bf2f((u16)(pr >> 16));
    } else {
      float2 v = ((const float2*)src)[off];
      v0 = v.x; v1 = v.y;
    }
    ((unsigned*)dst)[off] = (unsigned)f2h(v0) | ((unsigned)f2h(v1) << 16);
  } else if (i < NFP + NWP + NWG) {
    size_t off = i - NFP - NWP;
    int n = (int)(off >> 9), kp = (int)(off & 511);
    int k = kp * 2;
    float v0, v1;
    if (isb) {
      v0 = bf2f(((const u16*)wih)[(size_t)n * 1024 + k]);
      v1 = bf2f(((const u16*)wih)[(size_t)n * 1024 + k + 1]);
      if (k < 512) {
        v0 += bf2f(((const u16*)whh)[(size_t)n * 512 + k]);
        v1 += bf2f(((const u16*)whh)[(size_t)n * 512 + k + 1]);
      }
    } else {
      v0 = ((const float*)wih)[(size_t)n * 1024 + k];
      v1 = ((const float*)wih)[(size_t)n * 1024 + k + 1];
      if (k < 512) {
        v0 += ((const float*)whh)[(size_t)n * 512 + k];
        v1 += ((const float*)whh)[(size_t)n * 512 + k + 1];
      }
    }
    ((unsigned*)g_wg)[off] = (unsigned)f2h(v0) | ((unsigned)f2h(v1) << 16);
  }
}
#define CVT_BLOCKS ((int)((NFP + NWP + NWG + 255) / 256))

// ---- zero-init: Acat (1,048,576 dwords) + c (1,048,576 floats) ----
__global__ void k_init() {
  int i = blockIdx.x * 256 + threadIdx.x;            // grid 4096*256
  ((unsigned*)g_Acat)[i] = 0u;
  g_c[i] = 0.f;
}

// ---- per-graph start offsets from sorted graph_index ----
__global__ void k_offsets(const void* giv) {
  int n = blockIdx.x * 256 + threadIdx.x;
  if (n >= N_NODES) return;
  const int idx64 = g_idx64;
  int g = idx64 ? (int)((const long long*)giv)[n] : ((const int*)giv)[n];
  if (n == 0) {
    for (int x = 0; x <= g; ++x) g_start[x] = 0;
  } else {
    int gp = idx64 ? (int)((const long long*)giv)[n - 1] : ((const int*)giv)[n - 1];
    for (int x = gp + 1; x <= g; ++x) g_start[x] = n;
  }
  if (n == N_NODES - 1) {
    for (int x = g + 1; x <= NG; ++x) g_start[x] = N_NODES;
  }
}

// ---- GEMM 1: m = features @ W_m^T + b_m -> fp16, coalesced via LDS ----
__global__ __launch_bounds__(256) void k_gemm_m(const void* __restrict__ bias) {
  __shared__ u16 sm[64 * 512];                       // 64 KB staging for C-tile
  const int t = threadIdx.x, lid = t & 63, wid = t >> 6;
  const int m0 = blockIdx.x * 64 + (wid >> 1) * 32;
  const int rr = lid & 15, quad = lid >> 4;
  half8 Af[4][2];
  const u16* Ap = g_fb + (size_t)(m0 + rr) * DIM + quad * 8;
#pragma unroll
  for (int k = 0; k < 4; ++k) {
    Af[k][0] = *(const half8*)(Ap + k * 32);
    Af[k][1] = *(const half8*)(Ap + 16 * DIM + k * 32);
  }
  for (int nt = 0; nt < 8; ++nt) {
    const int n0 = nt * 64 + (wid & 1) * 32;
    const u16* Bp = g_wm + (size_t)(n0 + rr) * DIM + quad * 8;
    f32x4 acc[2][2] = {};
#pragma unroll
    for (int k = 0; k < 4; ++k) {
      half8 b0 = *(const half8*)(Bp + k * 32);
      half8 b1 = *(const half8*)(Bp + 16 * DIM + k * 32);
      acc[0][0] = __builtin_amdgcn_mfma_f32_16x16x32_f16(Af[k][0], b0, acc[0][0], 0, 0, 0);
      acc[0][1] = __builtin_amdgcn_mfma_f32_16x16x32_f16(Af[k][0], b1, acc[0][1], 0, 0, 0);
      acc[1][0] = __builtin_amdgcn_mfma_f32_16x16x32_f16(Af[k][1], b0, acc[1][0], 0, 0, 0);
      acc[1][1] = __builtin_amdgcn_mfma_f32_16x16x32_f16(Af[k][1], b1, acc[1][1], 0, 0, 0);
    }
#pragma unroll
    for (int i = 0; i < 2; ++i)
#pragma unroll
      for (int j = 0; j < 2; ++j) {
        int col = n0 + j * 16 + rr;
        float bv = rdf(bias, col);
#pragma unroll
        for (int r = 0; r < 4; ++r) {
          int rowl = (wid >> 1) * 32 + i * 16 + quad * 4 + r;
          sm[rowl * 512 + col] = f2h(acc[i][j][r] + bv);
        }
      }
  }
  __syncthreads();
#pragma unroll
  for (int it = 0; it < 16; ++it) {
    int row = it * 4 + wid;
    *(short8*)(g_m16 + (size_t)(blockIdx.x * 64 + row) * HD + lid * 8) =
        *(const short8*)(sm + row * 512 + lid * 8);
  }
}

// ---- GEMM 2: gates = [h|r] @ Wg^T  (M=2048,N=2048,K=1024), m97-style ----
__global__ __launch_bounds__(256) void k_gemm_gates() {
  __shared__ u16 As[128 * 64];                       // 16 KB, XOR-swizzled
  __shared__ u16 Bs[128 * 64];                       // 16 KB
  const int t = threadIdx.x, lid = t & 63, w = t >> 6;
  const int m0 = blockIdx.x * 128, n0 = blockIdx.y * 128;
  const int rr = lid & 15, quad = lid >> 4;
  const int rbase = w * 32;                          // this wave's staging rows
  const int rsub = lid >> 3;                         // 0..7
  const int cs = (lid & 7) ^ rsub;                   // swizzled k-chunk
  const int wm = (w >> 1) * 64, wn = (w & 1) * 64;
  f32x4 acc[4][4] = {};
  for (int kt = 0; kt < 16; ++kt) {
    const int k0 = kt * 64;
#pragma unroll
    for (int is = 0; is < 4; ++is) {
      int rl = rbase + is * 8;
      GLD16(g_Acat + (size_t)(m0 + rl + rsub) * 1024 + k0 + cs * 8, As + rl * 64);
      GLD16(g_wg   + (size_t)(n0 + rl + rsub) * 1024 + k0 + cs * 8, Bs + rl * 64);
    }
    __syncthreads();
#pragma unroll
    for (int kk = 0; kk < 2; ++kk) {
      const int qb = kk * 4 + quad;
      half8 af[4], bf[4];
#pragma unroll
      for (int i = 0; i < 4; ++i) {
        int m = wm + i * 16 + rr;
        af[i] = *(const half8*)(As + m * 64 + ((qb ^ (m & 7)) << 3));
      }
#pragma unroll
      for (int j = 0; j < 4; ++j) {
        int n = wn + j * 16 + rr;
        bf[j] = *(const half8*)(Bs + n * 64 + ((qb ^ (n & 7)) << 3));
      }
#pragma unroll
      for (int i = 0; i < 4; ++i)
#pragma unroll
        for (int j = 0; j < 4; ++j)
          acc[i][j] = __builtin_amdgcn_mfma_f32_16x16x32_f16(af[i], bf[j], acc[i][j], 0, 0, 0);
    }
    __syncthreads();
  }
#pragma unroll
  for (int i = 0; i < 4; ++i)
#pragma unroll
    for (int j = 0; j < 4; ++j)
#pragma unroll
      for (int r = 0; r < 4; ++r) {
        int row = m0 + wm + i * 16 + quad * 4 + r;
        int col = n0 + wn + j * 16 + rr;
        g_gates[(size_t)row * 2048 + col] = acc[i][j][r];
      }
}

// ---- LSTM cell elementwise ----
__global__ __launch_bounds__(256) void k_lstm(const void* __restrict__ b_ih,
                                              const void* __restrict__ b_hh,
                                              void* __restrict__ out) {
  int idx = blockIdx.x * 256 + threadIdx.x;          // NG*HD threads
  int g = idx >> 9, j = idx & 511;
  const float* grow = g_gates + (size_t)g * 2048;
  float xi = grow[j]        + rdf(b_ih, j)        + rdf(b_hh, j);
  float xf = grow[j + 512]  + rdf(b_ih, j + 512)  + rdf(b_hh, j + 512);
  float xg = grow[j + 1024] + rdf(b_ih, j + 1024) + rdf(b_hh, j + 1024);
  float xo = grow[j + 1536] + rdf(b_ih, j + 1536) + rdf(b_hh, j + 1536);
  float si = 1.f / (1.f + __expf(-xi));
  float sf = 1.f / (1.f + __expf(-xf));
  float tg = tanhf(xg);
  float so = 1.f / (1.f + __expf(-xo));
  float cn = sf * g_c[idx] + si * tg;
  float hn = so * tanhf(cn);
  g_c[idx] = cn;
  g_h[idx] = hn;
  g_Acat[(size_t)g * 1024 + j] = f2h(hn);
  if (g_isbf16) ((u16*)out)[(size_t)g * 1024 + j] = f2bf(hn);
  else          ((float*)out)[(size_t)g * 1024 + j] = hn;
}

// ---- attention: single-pass online softmax, 2-node unroll, 1 block/graph ----
__global__ __launch_bounds__(256) void k_attn(void* __restrict__ out) {
  const int g = blockIdx.x;
  const int t = threadIdx.x, lid = t & 63, wid = t >> 6;
  __shared__ float s_m[4], s_l[4];
  __shared__ float s_r[4][HD];
  const int s = g_start[g], e = g_start[g + 1];
  float hreg[8];
  *(float4*)(hreg)     = *(const float4*)(g_h + (size_t)g * HD + lid * 8);
  *(float4*)(hreg + 4) = *(const float4*)(g_h + (size_t)g * HD + lid * 8 + 4);
  float mrun = -3.0e38f, lsum = 0.f;
  float racc[8] = {0.f, 0.f, 0.f, 0.f, 0.f, 0.f, 0.f, 0.f};
  int n = s + wid;
  for (; n + 4 < e; n += 8) {
    half8 hv1 = *(const half8*)(g_m16 + (size_t)n * HD + lid * 8);
    half8 hv2 = *(const half8*)(g_m16 + (size_t)(n + 4) * HD + lid * 8);
    float mv1[8], mv2[8];
    float d1 = 0.f, d2 = 0.f;
#pragma unroll
    for (int j = 0; j < 8; ++j) {
      mv1[j] = (float)hv1[j]; mv2[j] = (float)hv2[j];
      d1 += mv1[j] * hreg[j]; d2 += mv2[j] * hreg[j];
    }
#pragma unroll
    for (int o = 32; o > 0; o >>= 1) {
      d1 += __shfl_xor(d1, o, 64);
      d2 += __shfl_xor(d2, o, 64);
    }
    float mnew = fmaxf(mrun, fmaxf(d1, d2));
    float sc = __expf(mrun - mnew);
    float w1 = __expf(d1 - mnew), w2 = __expf(d2 - mnew);
    lsum = lsum * sc + w1 + w2;
#pragma unroll
    for (int j = 0; j < 8; ++j) racc[j] = racc[j] * sc + w1 * mv1[j] + w2 * mv2[j];
    mrun = mnew;
  }
  if (n < e) {
    half8 hv = *(const half8*)(g_m16 + (size_t)n * HD + lid * 8);
    float mv[8];
    float d = 0.f;
#pragma unroll
    for (int j = 0; j < 8; ++j) { mv[j] = (float)hv[j]; d += mv[j] * hreg[j]; }
#pragma unroll
    for (int o = 32; o > 0; o >>= 1) d += __shfl_xor(d, o, 64);
    float mnew = fmaxf(mrun, d);
    float sc = __expf(mrun - mnew);
    float w = __expf(d - mnew);
    lsum = lsum * sc + w;
#pragma unroll
    for (int j = 0; j < 8; ++j) racc[j] = racc[j] * sc + w * mv[j];
    mrun = mnew;
  }
  if (lid == 0) s_m[wid] = mrun;
  __syncthreads();
  float gmax = fmaxf(fmaxf(s_m[0], s_m[1]), fmaxf(s_m[2], s_m[3]));
  float sc = (mrun > -1.0e38f) ? __expf(mrun - gmax) : 0.f;
#pragma unroll
  for (int j = 0; j < 8; ++j) s_r[wid][lid * 8 + j] = racc[j] * sc;
  if (lid == 0) s_l[wid] = lsum * sc;
  __syncthreads();
  float tot = s_l[0] + s_l[1] + s_l[2] + s_l[3];
  float inv = 1.f / (tot + 1e-7f);
  const int isb = g_isbf16;
  for (int d0 = t; d0 < HD; d0 += 256) {
    float rv = (s_r[0][d0] + s_r[1][d0] + s_r[2][d0] + s_r[3][d0]) * inv;
    g_Acat[(size_t)g * 1024 + 512 + d0] = f2h(rv);
    if (isb) ((u16*)out)[(size_t)g * 1024 + 512 + d0] = f2bf(rv);
    else     ((float*)out)[(size_t)g * 1024 + 512 + d0] = rv;
  }
}

extern "C" void kernel_launch(void* const* d_in, const int* in_sizes, int n_in,
                              void* d_out, int out_size, void* d_ws, size_t ws_size,
                              hipStream_t stream) {
  const void* features = d_in[0];
  const void* gidx     = d_in[1];
  const void* W_m      = d_in[2];
  const void* b_m      = d_in[3];
  const void* W_ih     = d_in[4];
  const void* W_hh     = d_in[5];
  const void* b_ih     = d_in[6];
  const void* b_hh     = d_in[7];

  k_detect<<<1, 256, 0, stream>>>(features, gidx);
  k_cvt_all<<<CVT_BLOCKS, 256, 0, stream>>>(features, W_m, W_ih, W_hh);
  k_init<<<4096, 256, 0, stream>>>();
  k_offsets<<<N_NODES / 256, 256, 0, stream>>>(gidx);
  k_gemm_m<<<N_NODES / 64, 256, 0, stream>>>(b_m);
  for (int loop = 0; loop < 3; ++loop) {
    k_gemm_gates<<<dim3(16, 16), 256, 0, stream>>>();
    k_lstm<<<NG * HD / 256, 256, 0, stream>>>(b_ih, b_hh, d_out);
    k_attn<<<NG, 256, 0, stream>>>(d_out);
  }
}

// Round 7
// 399.096 us; speedup vs baseline: 1.9559x; 1.0119x over previous
//
#include <hip/hip_runtime.h>

// ---- problem dims (fixed by setup_inputs) ----
#define N_NODES 131072
#define DIM     128
#define NG      2048
#define HD      512

typedef unsigned short u16;
typedef _Float16 half8 __attribute__((ext_vector_type(8)));
typedef short  short8 __attribute__((ext_vector_type(8)));
typedef float  f32x4  __attribute__((ext_vector_type(4)));

// ---- static device scratch (referenced ONLY from device code) ----
__device__ u16   g_fb[(size_t)N_NODES * DIM];     // features fp16 (33.5 MB)
__device__ u16   g_wm[(size_t)HD * DIM];          // W_m fp16
__device__ u16   g_wg[(size_t)2048 * 1024];       // [Wih[:,:H]+Whh | Wih[:,H:]] fp16
__device__ u16   g_m16[(size_t)N_NODES * HD];     // m fp16 (134 MB, L3-resident)
__device__ float g_gates[(size_t)NG * 2048];      // 16.8 MB
__device__ u16   g_Acat[(size_t)NG * 1024];       // [h | r] fp16, 4 MB
__device__ float g_c[(size_t)NG * HD];
__device__ float g_h[(size_t)NG * HD];
__device__ int   g_start[NG + 1];
__device__ int   g_isbf16;
__device__ int   g_idx64;

__device__ __forceinline__ float bf2f(u16 u) {
  unsigned v = ((unsigned)u) << 16;
  float f; __builtin_memcpy(&f, &v, 4); return f;
}
__device__ __forceinline__ u16 f2bf(float f) {
  unsigned u; __builtin_memcpy(&u, &f, 4);
  u += 0x7FFFu + ((u >> 16) & 1u);
  return (u16)(u >> 16);
}
__device__ __forceinline__ u16 f2h(float f) {
  _Float16 h = (_Float16)f; u16 u; __builtin_memcpy(&u, &h, 2); return u;
}
__device__ __forceinline__ float rdf(const void* p, int i) {
  return g_isbf16 ? bf2f(((const u16*)p)[i]) : ((const float*)p)[i];
}

#define GLD16(gp, lp) __builtin_amdgcn_global_load_lds(                          \
    (const __attribute__((address_space(1))) void*)(gp),                         \
    (__attribute__((address_space(3))) void*)(lp), 16, 0, 0)

// ---- dtype detection ----
__global__ void k_detect(const void* feat, const void* gi) {
  __shared__ int cnt;
  if (threadIdx.x == 0) cnt = 0;
  __syncthreads();
  u16 u = ((const u16*)feat)[threadIdx.x];
  float v = bf2f(u);
  float a = fabsf(v);
  int ok = (v == v) && a >= 1e-6f && a <= 1e6f;
  atomicAdd(&cnt, ok);
  __syncthreads();
  if (threadIdx.x == 0) {
    g_isbf16 = (cnt >= 230);
    g_idx64 = (((const int*)gi)[N_NODES - 1] == 0);
  }
}

// ---- conversion: features/W_m -> fp16; build Wg = [Wih_l + Whh | Wih_r] fp16
#define NFP ((size_t)N_NODES * DIM / 2)
#define NWP ((size_t)HD * DIM / 2)
#define NWG ((size_t)2048 * 1024 / 2)
__global__ __launch_bounds__(256) void k_cvt_all(const void* f, const void* wm,
                                                 const void* wih, const void* whh) {
  const int isb = g_isbf16;
  size_t i = (size_t)blockIdx.x * 256 + threadIdx.x;
  if (i < NFP + NWP) {
    const void* src = (i < NFP) ? f : wm;
    u16* dst = (i < NFP) ? g_fb : g_wm;
    size_t off = (i < NFP) ? i : i - NFP;
    float v0, v1;
    if (isb) {
      unsigned pr = ((const unsigned*)src)[off];
      v0 = bf2f((u16)pr); v1 = bf2f((u16)(pr >> 16));
    } else {
      float2 v = ((const float2*)src)[off];
      v0 = v.x; v1 = v.y;
    }
    ((unsigned*)dst)[off] = (unsigned)f2h(v0) | ((unsigned)f2h(v1) << 16);
  } else if (i < NFP + NWP + NWG) {
    size_t off = i - NFP - NWP;
    int n = (int)(off >> 9), kp = (int)(off & 511);
    int k = kp * 2;
    float v0, v1;
    if (isb) {
      v0 = bf2f(((const u16*)wih)[(size_t)n * 1024 + k]);
      v1 = bf2f(((const u16*)wih)[(size_t)n * 1024 + k + 1]);
      if (k < 512) {
        v0 += bf2f(((const u16*)whh)[(size_t)n * 512 + k]);
        v1 += bf2f(((const u16*)whh)[(size_t)n * 512 + k + 1]);
      }
    } else {
      v0 = ((const float*)wih)[(size_t)n * 1024 + k];
      v1 = ((const float*)wih)[(size_t)n * 1024 + k + 1];
      if (k < 512) {
        v0 += ((const float*)whh)[(size_t)n * 512 + k];
        v1 += ((const float*)whh)[(size_t)n * 512 + k + 1];
      }
    }
    ((unsigned*)g_wg)[off] = (unsigned)f2h(v0) | ((unsigned)f2h(v1) << 16);
  }
}
#define CVT_BLOCKS ((int)((NFP + NWP + NWG + 255) / 256))

// ---- zero-init: Acat (1,048,576 dwords) + c (1,048,576 floats) ----
__global__ void k_init() {
  int i = blockIdx.x * 256 + threadIdx.x;            // grid 4096*256
  ((unsigned*)g_Acat)[i] = 0u;
  g_c[i] = 0.f;
}

// ---- per-graph start offsets from sorted graph_index ----
__global__ void k_offsets(const void* giv) {
  int n = blockIdx.x * 256 + threadIdx.x;
  if (n >= N_NODES) return;
  const int idx64 = g_idx64;
  int g = idx64 ? (int)((const long long*)giv)[n] : ((const int*)giv)[n];
  if (n == 0) {
    for (int x = 0; x <= g; ++x) g_start[x] = 0;
  } else {
    int gp = idx64 ? (int)((const long long*)giv)[n - 1] : ((const int*)giv)[n - 1];
    for (int x = gp + 1; x <= g; ++x) g_start[x] = n;
  }
  if (n == N_NODES - 1) {
    for (int x = g + 1; x <= NG; ++x) g_start[x] = N_NODES;
  }
}

// ---- GEMM 1: m = features @ W_m^T + b_m -> fp16
// Transposed-MFMA epilogue: lane holds 4 consecutive cols -> packed dwordx2.
__global__ __launch_bounds__(256) void k_gemm_m(const void* __restrict__ bias) {
  const int t = threadIdx.x, lid = t & 63, wid = t >> 6;
  const int m0 = blockIdx.x * 64 + (wid >> 1) * 32;
  const int rr = lid & 15, quad = lid >> 4;
  // F-fragments (B-operand) for this wave's 32 rows, register-resident
  half8 Ff[4][2];
  const u16* Ap = g_fb + (size_t)(m0 + rr) * DIM + quad * 8;
#pragma unroll
  for (int k = 0; k < 4; ++k) {
    Ff[k][0] = *(const half8*)(Ap + k * 32);
    Ff[k][1] = *(const half8*)(Ap + 16 * DIM + k * 32);
  }
  for (int nt = 0; nt < 8; ++nt) {
    const int n0 = nt * 64 + (wid & 1) * 32;
    const u16* Bp = g_wm + (size_t)(n0 + rr) * DIM + quad * 8;
    f32x4 acc[2][2] = {};                            // [i = m-tile][j = n-tile]
#pragma unroll
    for (int k = 0; k < 4; ++k) {
      half8 w0 = *(const half8*)(Bp + k * 32);
      half8 w1 = *(const half8*)(Bp + 16 * DIM + k * 32);
      // D = W_tile @ F_tile^T: D[row=quad*4+r -> n][col=rr -> m]
      acc[0][0] = __builtin_amdgcn_mfma_f32_16x16x32_f16(w0, Ff[k][0], acc[0][0], 0, 0, 0);
      acc[0][1] = __builtin_amdgcn_mfma_f32_16x16x32_f16(w1, Ff[k][0], acc[0][1], 0, 0, 0);
      acc[1][0] = __builtin_amdgcn_mfma_f32_16x16x32_f16(w0, Ff[k][1], acc[1][0], 0, 0, 0);
      acc[1][1] = __builtin_amdgcn_mfma_f32_16x16x32_f16(w1, Ff[k][1], acc[1][1], 0, 0, 0);
    }
#pragma unroll
    for (int i = 0; i < 2; ++i)
#pragma unroll
      for (int j = 0; j < 2; ++j) {
        const int row = m0 + i * 16 + rr;
        const int c0 = n0 + j * 16 + quad * 4;
        u16 h[4];
#pragma unroll
        for (int r = 0; r < 4; ++r) h[r] = f2h(acc[i][j][r] + rdf(bias, c0 + r));
        unsigned lo = (unsigned)h[0] | ((unsigned)h[1] << 16);
        unsigned hi = (unsigned)h[2] | ((unsigned)h[3] << 16);
        *(uint2*)(g_m16 + (size_t)row * HD + c0) = make_uint2(lo, hi);
      }
  }
}

// ---- GEMM 2: gates = [h|r] @ Wg^T  (M=2048,N=2048,K=1024), 64x64 tiles ----
__global__ __launch_bounds__(256) void k_gemm_gates() {
  __shared__ u16 As[64 * 64];                        // 8 KB, XOR-swizzled
  __shared__ u16 Bs[64 * 64];                        // 8 KB
  const int t = threadIdx.x, lid = t & 63, w = t >> 6;
  const int m0 = blockIdx.x * 64, n0 = blockIdx.y * 64;
  const int rr = lid & 15, quad = lid >> 4;
  const int rsub = lid >> 3;                         // 0..7
  const int cs = (lid & 7) ^ rsub;                   // swizzled k-chunk
  const int wm = (w >> 1) * 32, wn = (w & 1) * 32;
  f32x4 acc[2][2] = {};
  for (int kt = 0; kt < 16; ++kt) {
    const int k0 = kt * 64;
    GLD16(g_Acat + (size_t)(m0 + w * 16 + rsub) * 1024 + k0 + cs * 8, As + (w * 16) * 64);
    GLD16(g_Acat + (size_t)(m0 + w * 16 + 8 + rsub) * 1024 + k0 + cs * 8, As + (w * 16 + 8) * 64);
    GLD16(g_wg   + (size_t)(n0 + w * 16 + rsub) * 1024 + k0 + cs * 8, Bs + (w * 16) * 64);
    GLD16(g_wg   + (size_t)(n0 + w * 16 + 8 + rsub) * 1024 + k0 + cs * 8, Bs + (w * 16 + 8) * 64);
    __syncthreads();
#pragma unroll
    for (int kk = 0; kk < 2; ++kk) {
      const int qb = kk * 4 + quad;
      const int sw = (qb ^ (rr & 7)) << 3;
      half8 af[2], bfr[2];
#pragma unroll
      for (int i = 0; i < 2; ++i) af[i]  = *(const half8*)(As + (wm + i * 16 + rr) * 64 + sw);
#pragma unroll
      for (int j = 0; j < 2; ++j) bfr[j] = *(const half8*)(Bs + (wn + j * 16 + rr) * 64 + sw);
      // D = Wg_tile @ Acat_tile^T -> lane holds 4 consecutive gate-cols
#pragma unroll
      for (int i = 0; i < 2; ++i)
#pragma unroll
        for (int j = 0; j < 2; ++j)
          acc[i][j] = __builtin_amdgcn_mfma_f32_16x16x32_f16(bfr[j], af[i], acc[i][j], 0, 0, 0);
    }
    __syncthreads();
  }
#pragma unroll
  for (int i = 0; i < 2; ++i)
#pragma unroll
    for (int j = 0; j < 2; ++j) {
      const int row = m0 + wm + i * 16 + rr;
      const int c0 = n0 + wn + j * 16 + quad * 4;
      *(f32x4*)(g_gates + (size_t)row * 2048 + c0) = acc[i][j];
    }
}

// ---- LSTM cell elementwise ----
__global__ __launch_bounds__(256) void k_lstm(const void* __restrict__ b_ih,
                                              const void* __restrict__ b_hh,
                                              void* __restrict__ out) {
  int idx = blockIdx.x * 256 + threadIdx.x;          // NG*HD threads
  int g = idx >> 9, j = idx & 511;
  const float* grow = g_gates + (size_t)g * 2048;
  float xi = grow[j]        + rdf(b_ih, j)        + rdf(b_hh, j);
  float xf = grow[j + 512]  + rdf(b_ih, j + 512)  + rdf(b_hh, j + 512);
  float xg = grow[j + 1024] + rdf(b_ih, j + 1024) + rdf(b_hh, j + 1024);
  float xo = grow[j + 1536] + rdf(b_ih, j + 1536) + rdf(b_hh, j + 1536);
  float si = 1.f / (1.f + __expf(-xi));
  float sf = 1.f / (1.f + __expf(-xf));
  float tg = tanhf(xg);
  float so = 1.f / (1.f + __expf(-xo));
  float cn = sf * g_c[idx] + si * tg;
  float hn = so * tanhf(cn);
  g_c[idx] = cn;
  g_h[idx] = hn;
  g_Acat[(size_t)g * 1024 + j] = f2h(hn);
  if (g_isbf16) ((u16*)out)[(size_t)g * 1024 + j] = f2bf(hn);
  else          ((float*)out)[(size_t)g * 1024 + j] = hn;
}

// ---- attention: single-pass online softmax, 2-node unroll, 1 block/graph ----
__global__ __launch_bounds__(256) void k_attn(void* __restrict__ out) {
  const int g = blockIdx.x;
  const int t = threadIdx.x, lid = t & 63, wid = t >> 6;
  __shared__ float s_m[4], s_l[4];
  __shared__ float s_r[4][HD];
  const int s = g_start[g], e = g_start[g + 1];
  float hreg[8];
  *(float4*)(hreg)     = *(const float4*)(g_h + (size_t)g * HD + lid * 8);
  *(float4*)(hreg + 4) = *(const float4*)(g_h + (size_t)g * HD + lid * 8 + 4);
  float mrun = -3.0e38f, lsum = 0.f;
  float racc[8] = {0.f, 0.f, 0.f, 0.f, 0.f, 0.f, 0.f, 0.f};
  int n = s + wid;
  for (; n + 4 < e; n += 8) {
    half8 hv1 = *(const half8*)(g_m16 + (size_t)n * HD + lid * 8);
    half8 hv2 = *(const half8*)(g_m16 + (size_t)(n + 4) * HD + lid * 8);
    float mv1[8], mv2[8];
    float d1 = 0.f, d2 = 0.f;
#pragma unroll
    for (int j = 0; j < 8; ++j) {
      mv1[j] = (float)hv1[j]; mv2[j] = (float)hv2[j];
      d1 += mv1[j] * hreg[j]; d2 += mv2[j] * hreg[j];
    }
#pragma unroll
    for (int o = 32; o > 0; o >>= 1) {
      d1 += __shfl_xor(d1, o, 64);
      d2 += __shfl_xor(d2, o, 64);
    }
    float mnew = fmaxf(mrun, fmaxf(d1, d2));
    float sc = __expf(mrun - mnew);
    float w1 = __expf(d1 - mnew), w2 = __expf(d2 - mnew);
    lsum = lsum * sc + w1 + w2;
#pragma unroll
    for (int j = 0; j < 8; ++j) racc[j] = racc[j] * sc + w1 * mv1[j] + w2 * mv2[j];
    mrun = mnew;
  }
  if (n < e) {
    half8 hv = *(const half8*)(g_m16 + (size_t)n * HD + lid * 8);
    float mv[8];
    float d = 0.f;
#pragma unroll
    for (int j = 0; j < 8; ++j) { mv[j] = (float)hv[j]; d += mv[j] * hreg[j]; }
#pragma unroll
    for (int o = 32; o > 0; o >>= 1) d += __shfl_xor(d, o, 64);
    float mnew = fmaxf(mrun, d);
    float sc = __expf(mrun - mnew);
    float w = __expf(d - mnew);
    lsum = lsum * sc + w;
#pragma unroll
    for (int j = 0; j < 8; ++j) racc[j] = racc[j] * sc + w * mv[j];
    mrun = mnew;
  }
  if (lid == 0) s_m[wid] = mrun;
  __syncthreads();
  float gmax = fmaxf(fmaxf(s_m[0], s_m[1]), fmaxf(s_m[2], s_m[3]));
  float sc = (mrun > -1.0e38f) ? __expf(mrun - gmax) : 0.f;
#pragma unroll
  for (int j = 0; j < 8; ++j) s_r[wid][lid * 8 + j] = racc[j] * sc;
  if (lid == 0) s_l[wid] = lsum * sc;
  __syncthreads();
  float tot = s_l[0] + s_l[1] + s_l[2] + s_l[3];
  float inv = 1.f / (tot + 1e-7f);
  const int isb = g_isbf16;
  for (int d0 = t; d0 < HD; d0 += 256) {
    float rv = (s_r[0][d0] + s_r[1][d0] + s_r[2][d0] + s_r[3][d0]) * inv;
    g_Acat[(size_t)g * 1024 + 512 + d0] = f2h(rv);
    if (isb) ((u16*)out)[(size_t)g * 1024 + 512 + d0] = f2bf(rv);
    else     ((float*)out)[(size_t)g * 1024 + 512 + d0] = rv;
  }
}

extern "C" void kernel_launch(void* const* d_in, const int* in_sizes, int n_in,
                              void* d_out, int out_size, void* d_ws, size_t ws_size,
                              hipStream_t stream) {
  const void* features = d_in[0];
  const void* gidx     = d_in[1];
  const void* W_m      = d_in[2];
  const void* b_m      = d_in[3];
  const void* W_ih     = d_in[4];
  const void* W_hh     = d_in[5];
  const void* b_ih     = d_in[6];
  const void* b_hh     = d_in[7];

  k_detect<<<1, 256, 0, stream>>>(features, gidx);
  k_cvt_all<<<CVT_BLOCKS, 256, 0, stream>>>(features, W_m, W_ih, W_hh);
  k_init<<<4096, 256, 0, stream>>>();
  k_offsets<<<N_NODES / 256, 256, 0, stream>>>(gidx);
  k_gemm_m<<<N_NODES / 64, 256, 0, stream>>>(b_m);
  for (int loop = 0; loop < 3; ++loop) {
    k_gemm_gates<<<dim3(32, 32), 256, 0, stream>>>();
    k_lstm<<<NG * HD / 256, 256, 0, stream>>>(b_ih, b_hh, d_out);
    k_attn<<<NG, 256, 0, stream>>>(d_out);
  }
}